// Round 1
// baseline (212.565 us; speedup 1.0000x reference)
//
#include <hip/hip_runtime.h>

typedef float f4 __attribute__((ext_vector_type(4)));

constexpr int B_ = 2, A_ = 5, N_ = 1000, K_ = 16, F_ = 256, E_ = 3;
constexpr int RTOT = B_ * N_;      // 2000 (b,n) rows
constexpr int TILE = 16;           // rows per block
constexpr int NT   = RTOT / TILE;  // 125 tiles

// ---------------------------------------------------------------------------
// Kernel 1: per (a, row-tile): gather neighbor features, bucket-sum by edge
// type into LDS S[16][768], then GEMM S[16][768] x W_stack[768][256] -> pw.
// pw written into d_out (used as scratch until k_hop overwrites it).
// ---------------------------------------------------------------------------
__global__ __launch_bounds__(256) void k_gather_transform(
    const float* __restrict__ nf, const int* __restrict__ nn_idx,
    const int* __restrict__ et, const float* __restrict__ W,
    const float* __restrict__ bias, float* __restrict__ pw)
{
  __shared__ float S[TILE][E_ * F_];   // 16 x 768 = 48 KiB
  __shared__ float CNT[TILE][E_];
  const int a   = blockIdx.y;
  const int r0  = blockIdx.x * TILE;
  const int tid = threadIdx.x;

  // ---- phase 1: gather + per-edge-type reduce (thread = feature f = tid) ---
  for (int row = 0; row < TILE; ++row) {
    const int r  = r0 + row;
    const int bb = r / N_, n = r - bb * N_;
    const int eoff = ((bb * A_ + a) * N_ + n) * K_;
    const int* __restrict__ ip = nn_idx + eoff;
    const int* __restrict__ ep = et + eoff;
    const float* __restrict__ slab = nf + (bb * A_ + a) * N_ * F_ + tid;
    float a0 = 0.f, a1 = 0.f, a2 = 0.f;
    int   c0 = 0,   c1 = 0,   c2 = 0;
#pragma unroll
    for (int k = 0; k < K_; ++k) {
      const int id = ip[k];
      const int e  = ep[k];
      const float v = slab[id * F_];
      if (e == 0)      { a0 += v; ++c0; }
      else if (e == 1) { a1 += v; ++c1; }
      else             { a2 += v; ++c2; }
    }
    S[row][tid]          = a0;
    S[row][F_ + tid]     = a1;
    S[row][2 * F_ + tid] = a2;
    if (tid == 0) { CNT[row][0] = (float)c0; CNT[row][1] = (float)c1; CNT[row][2] = (float)c2; }
  }
  __syncthreads();

  // ---- phase 2: GEMM, 4 rows x 4 cols per thread -------------------------
  const int tx = tid & 63, ty = tid >> 6;   // within a wave, ty is uniform
  const float* __restrict__ Wa = W + a * (E_ * F_ * F_);  // [768][256]
  float acc[4][4] = {{0.f, 0.f, 0.f, 0.f}};
  for (int kk = 0; kk < E_ * F_; kk += 4) {
    f4 w[4], s[4];
#pragma unroll
    for (int u = 0; u < 4; ++u)
      w[u] = *reinterpret_cast<const f4*>(Wa + (kk + u) * F_ + tx * 4);
#pragma unroll
    for (int rr = 0; rr < 4; ++rr)
      s[rr] = *reinterpret_cast<const f4*>(&S[ty * 4 + rr][kk]);
#pragma unroll
    for (int u = 0; u < 4; ++u)
#pragma unroll
      for (int rr = 0; rr < 4; ++rr)
#pragma unroll
        for (int j = 0; j < 4; ++j)
          acc[rr][j] += s[rr][u] * w[u][j];
  }

  // ---- epilogue: + cnt_e * b[a,e,:], /K, relu, store ---------------------
  const float* __restrict__ ba = bias + a * (E_ * F_);
  const f4 b0 = *reinterpret_cast<const f4*>(ba + 0 * F_ + tx * 4);
  const f4 b1 = *reinterpret_cast<const f4*>(ba + 1 * F_ + tx * 4);
  const f4 b2v = *reinterpret_cast<const f4*>(ba + 2 * F_ + tx * 4);
#pragma unroll
  for (int rr = 0; rr < 4; ++rr) {
    const int row = ty * 4 + rr;
    const int r   = r0 + row;
    const int bb  = r / N_, n = r - bb * N_;
    f4 v;
#pragma unroll
    for (int j = 0; j < 4; ++j) {
      float x = (acc[rr][j] + CNT[row][0] * b0[j] + CNT[row][1] * b1[j] +
                 CNT[row][2] * b2v[j]) * (1.0f / K_);
      v[j] = fmaxf(x, 0.f);
    }
    *reinterpret_cast<f4*>(pw + ((bb * A_ + a) * N_ + n) * F_ + tx * 4) = v;
  }
}

// ---------------------------------------------------------------------------
// Kernel 2: mutual[b,n,f] = sum_a pw[b,a,n,f]
// ---------------------------------------------------------------------------
__global__ __launch_bounds__(256) void k_mutual(
    const float* __restrict__ pw, float* __restrict__ mut)
{
  const int i = blockIdx.x * 256 + threadIdx.x;   // over B*N*F = 512000
  const int f  = i & (F_ - 1);
  const int bn = i >> 8;          // = bb*N_ + n
  const int bb = bn / N_, n = bn - bb * N_;
  float s = 0.f;
#pragma unroll
  for (int a = 0; a < A_; ++a)
    s += pw[((bb * A_ + a) * N_ + n) * F_ + f];
  mut[i] = s;
}

// ---------------------------------------------------------------------------
// Kernel 3: hop = relu(pw*W1[a] + mutual*W2[a] + b2[a]) + nfeature.
// io == d_out holds pw on entry; each block reads exactly the 16 rows (for
// its own a) that it later overwrites -> no cross-block hazard.
// ---------------------------------------------------------------------------
__global__ __launch_bounds__(256) void k_hop(
    float* io, const float* __restrict__ mut,
    const float* __restrict__ W1, const float* __restrict__ W2,
    const float* __restrict__ b2, const float* __restrict__ nf)
{
  __shared__ float P[TILE][F_];   // 16 KiB
  __shared__ float M[TILE][F_];   // 16 KiB
  const int a   = blockIdx.y;
  const int r0  = blockIdx.x * TILE;
  const int tid = threadIdx.x;

  for (int row = 0; row < TILE; ++row) {
    const int r  = r0 + row;
    const int bb = r / N_, n = r - bb * N_;
    P[row][tid] = io[((bb * A_ + a) * N_ + n) * F_ + tid];
    M[row][tid] = mut[(bb * N_ + n) * F_ + tid];
  }
  __syncthreads();

  const int tx = tid & 63, ty = tid >> 6;
  const float* __restrict__ W1a = W1 + a * (F_ * F_);
  const float* __restrict__ W2a = W2 + a * (F_ * F_);
  float acc[4][4] = {{0.f, 0.f, 0.f, 0.f}};
  for (int kk = 0; kk < F_; kk += 4) {
    f4 w1[4], w2[4], sp[4], sm[4];
#pragma unroll
    for (int u = 0; u < 4; ++u) {
      w1[u] = *reinterpret_cast<const f4*>(W1a + (kk + u) * F_ + tx * 4);
      w2[u] = *reinterpret_cast<const f4*>(W2a + (kk + u) * F_ + tx * 4);
    }
#pragma unroll
    for (int rr = 0; rr < 4; ++rr) {
      sp[rr] = *reinterpret_cast<const f4*>(&P[ty * 4 + rr][kk]);
      sm[rr] = *reinterpret_cast<const f4*>(&M[ty * 4 + rr][kk]);
    }
#pragma unroll
    for (int u = 0; u < 4; ++u)
#pragma unroll
      for (int rr = 0; rr < 4; ++rr)
#pragma unroll
        for (int j = 0; j < 4; ++j)
          acc[rr][j] += sp[rr][u] * w1[u][j] + sm[rr][u] * w2[u][j];
  }

  const f4 bb2 = *reinterpret_cast<const f4*>(b2 + a * F_ + tx * 4);
#pragma unroll
  for (int rr = 0; rr < 4; ++rr) {
    const int row = ty * 4 + rr;
    const int r   = r0 + row;
    const int bb  = r / N_, n = r - bb * N_;
    const int o   = ((bb * A_ + a) * N_ + n) * F_ + tx * 4;
    const f4 nfv  = *reinterpret_cast<const f4*>(nf + o);
    f4 v;
#pragma unroll
    for (int j = 0; j < 4; ++j)
      v[j] = fmaxf(acc[rr][j] + bb2[j], 0.f) + nfv[j];
    *reinterpret_cast<f4*>(io + o) = v;
  }
}

// ---------------------------------------------------------------------------
extern "C" void kernel_launch(void* const* d_in, const int* in_sizes, int n_in,
                              void* d_out, int out_size, void* d_ws, size_t ws_size,
                              hipStream_t stream)
{
  const float* nf     = (const float*)d_in[0];
  const int*   nn_idx = (const int*)  d_in[1];
  const int*   et     = (const int*)  d_in[2];
  const float* W      = (const float*)d_in[3];
  const float* bias   = (const float*)d_in[4];
  const float* W1     = (const float*)d_in[5];
  const float* W2     = (const float*)d_in[6];
  const float* b2     = (const float*)d_in[7];
  float* out = (float*)d_out;
  float* mut = (float*)d_ws;   // B*N*F floats = 2 MiB scratch

  dim3 gtile(NT, A_);
  k_gather_transform<<<gtile, 256, 0, stream>>>(nf, nn_idx, et, W, bias, out);
  k_mutual<<<dim3((B_ * N_ * F_) / 256), 256, 0, stream>>>(out, mut);
  k_hop<<<gtile, 256, 0, stream>>>(out, mut, W1, W2, b2, nf);
}

// Round 2
// 116.770 us; speedup vs baseline: 1.8204x; 1.8204x over previous
//
#include <hip/hip_runtime.h>

typedef float f32x4 __attribute__((ext_vector_type(4)));
typedef __bf16 bf16x8 __attribute__((ext_vector_type(8)));
typedef unsigned short u16x8 __attribute__((ext_vector_type(8)));

constexpr int B_ = 2, A_ = 5, N_ = 1000, K_ = 16, F_ = 256, E_ = 3;
constexpr int TILE = 16;
constexpr int NT   = (B_ * N_) / TILE;   // 125 row-tiles
constexpr int KS1  = (E_ * F_) / 32;     // 24 k-steps for gather GEMM (K=768)
constexpr int KS2  = (2 * F_) / 32;      // 16 k-steps for hop GEMM (K=512)
constexpr int NTL  = F_ / 16;            // 16 n-tiles of 16 cols

// workspace layout (bytes)
constexpr size_t SZ_WPK  = (size_t)A_ * KS1 * NTL * 512 * 2;  // 1,966,080
constexpr size_t OFF_W12 = SZ_WPK;
constexpr size_t SZ_W12  = (size_t)A_ * KS2 * NTL * 512 * 2;  // 1,310,720
constexpr size_t OFF_MUT = OFF_W12 + SZ_W12;                  // fp32 B*N*F

__device__ __forceinline__ unsigned short f2bf(float x) {
  unsigned int u = __builtin_bit_cast(unsigned int, x);
  u += 0x7fffu + ((u >> 16) & 1u);          // round-to-nearest-even
  return (unsigned short)(u >> 16);
}

// ---------------------------------------------------------------------------
// k_pack: pre-convert W / [W1;W2] to bf16 in per-lane MFMA B-fragment order:
//   Wpk[a][t][nt][lane][8] = W[a][k = t*32+(lane>>4)*8+j][n = nt*16+(lane&15)]
// Each thread produces one lane's 8 contiguous bf16 (one 16B store).
// ---------------------------------------------------------------------------
__global__ __launch_bounds__(256) void k_pack(
    const float* __restrict__ W, const float* __restrict__ W1,
    const float* __restrict__ W2, unsigned short* __restrict__ wpk,
    unsigned short* __restrict__ w12)
{
  const int id = blockIdx.x * 256 + threadIdx.x;
  const int T1 = A_ * KS1 * NTL * 64;   // 122880
  const int T2 = A_ * KS2 * NTL * 64;   // 81920
  if (id < T1) {
    const int lane = id & 63, nt = (id >> 6) & 15;
    const int r = id >> 10, t = r % KS1, a = r / KS1;
    const int k0 = t * 32 + (lane >> 4) * 8;
    const int n  = nt * 16 + (lane & 15);
    const float* src = W + ((size_t)a * E_ * F_ + k0) * F_ + n;
    u16x8 v;
#pragma unroll
    for (int j = 0; j < 8; ++j) v[j] = f2bf(src[(size_t)j * F_]);
    *reinterpret_cast<u16x8*>(wpk + (size_t)id * 8) = v;
  } else if (id < T1 + T2) {
    const int p = id - T1;
    const int lane = p & 63, nt = (p >> 6) & 15;
    const int r = p >> 10, t = r % KS2, a = r / KS2;
    const int k0 = t * 32 + (lane >> 4) * 8;
    const int n  = nt * 16 + (lane & 15);
    u16x8 v;
#pragma unroll
    for (int j = 0; j < 8; ++j) {
      const int k = k0 + j;
      const float s = (k < F_) ? W1[((size_t)a * F_ + k) * F_ + n]
                               : W2[((size_t)a * F_ + (k - F_)) * F_ + n];
      v[j] = f2bf(s);
    }
    *reinterpret_cast<u16x8*>(w12 + (size_t)p * 8) = v;
  }
}

// ---------------------------------------------------------------------------
// k_gather_mfma: per (a, 16-row tile): gather + bucket-sum by edge type into
// XOR-swizzled bf16 LDS S[16][768], then MFMA GEMM vs packed W -> pw (fp32,
// written to d_out scratch).
// ---------------------------------------------------------------------------
__global__ __launch_bounds__(256) void k_gather_mfma(
    const float* __restrict__ nf, const int* __restrict__ nn_idx,
    const int* __restrict__ et, const unsigned short* __restrict__ wpk,
    const float* __restrict__ bias, float* __restrict__ pw)
{
  __shared__ alignas(16) unsigned short S[TILE * E_ * F_];  // 24 KiB
  __shared__ float CNT[TILE][4];
  const int a   = blockIdx.y;
  const int r0  = blockIdx.x * TILE;
  const int tid = threadIdx.x;

  // phase 1: gather-reduce; thread = feature f = tid
  for (int row = 0; row < TILE; ++row) {
    const int r  = r0 + row;
    const int bb = r / N_, n = r - bb * N_;
    const int eoff = ((bb * A_ + a) * N_ + n) * K_;
    const int* __restrict__ ip = nn_idx + eoff;
    const int* __restrict__ ep = et + eoff;
    const float* __restrict__ slab = nf + (size_t)(bb * A_ + a) * N_ * F_ + tid;
    float a0 = 0.f, a1 = 0.f, a2 = 0.f;
    int   c0 = 0,   c1 = 0,   c2 = 0;
#pragma unroll
    for (int k = 0; k < K_; ++k) {
      const int id = ip[k];
      const int e  = ep[k];
      const float v = slab[(size_t)id * F_];
      if (e == 0)      { a0 += v; ++c0; }
      else if (e == 1) { a1 += v; ++c1; }
      else             { a2 += v; ++c2; }
    }
    const int sw = (row & 7) << 3;   // XOR swizzle, 16B granule in short-index space
    S[(row * 768 + tid)           ^ sw] = f2bf(a0);
    S[(row * 768 + F_ + tid)      ^ sw] = f2bf(a1);
    S[(row * 768 + 2 * F_ + tid)  ^ sw] = f2bf(a2);
    if (tid == 0) { CNT[row][0] = (float)c0; CNT[row][1] = (float)c1; CNT[row][2] = (float)c2; }
  }
  __syncthreads();

  // phase 2: MFMA GEMM [16 x 768] x [768 x 256]; wave wv owns cols 64*wv..+63
  const int lane = tid & 63, wv = tid >> 6;
  const int arow = lane & 15, kg = lane >> 4;
  const unsigned short* __restrict__ Wp = wpk + (size_t)a * KS1 * NTL * 512;
  f32x4 acc[4];
#pragma unroll
  for (int m = 0; m < 4; ++m) acc[m] = (f32x4){0.f, 0.f, 0.f, 0.f};
  const int sbase_sw = (arow & 7) << 3;
  for (int t = 0; t < KS1; ++t) {
    const int si = (arow * 768 + t * 32 + kg * 8) ^ sbase_sw;
    const bf16x8 af = *reinterpret_cast<const bf16x8*>(&S[si]);
#pragma unroll
    for (int m = 0; m < 4; ++m) {
      const int nt = wv * 4 + m;
      const bf16x8 bf = *reinterpret_cast<const bf16x8*>(
          Wp + ((size_t)(t * NTL + nt) * 64 + lane) * 8);
      acc[m] = __builtin_amdgcn_mfma_f32_16x16x32_bf16(af, bf, acc[m], 0, 0, 0);
    }
  }

  // epilogue: + cnt_e * b[a,e,col], /K, relu, store fp32
  const float* __restrict__ ba = bias + a * E_ * F_;
  const int orow0 = kg * 4;
#pragma unroll
  for (int m = 0; m < 4; ++m) {
    const int col = (wv * 4 + m) * 16 + arow;
    const float b0 = ba[col], b1 = ba[F_ + col], b2v = ba[2 * F_ + col];
#pragma unroll
    for (int rr = 0; rr < 4; ++rr) {
      const int row = orow0 + rr;
      float x = (acc[m][rr] + CNT[row][0] * b0 + CNT[row][1] * b1 +
                 CNT[row][2] * b2v) * (1.0f / K_);
      x = fmaxf(x, 0.f);
      const int r = r0 + row, bb = r / N_, n = r - bb * N_;
      pw[((size_t)(bb * A_ + a) * N_ + n) * F_ + col] = x;
    }
  }
}

// ---------------------------------------------------------------------------
// k_mutual: mut[b,n,f] = sum_a pw[b,a,n,f]   (fp32)
// ---------------------------------------------------------------------------
__global__ __launch_bounds__(256) void k_mutual(
    const float* __restrict__ pw, float* __restrict__ mut)
{
  const int i  = blockIdx.x * 256 + threadIdx.x;  // over B*N*F = 512000
  const int f  = i & (F_ - 1);
  const int bn = i >> 8;
  const int bb = bn / N_, n = bn - bb * N_;
  float s = 0.f;
#pragma unroll
  for (int a = 0; a < A_; ++a)
    s += pw[((size_t)(bb * A_ + a) * N_ + n) * F_ + f];
  mut[i] = s;
}

// ---------------------------------------------------------------------------
// k_hop_mfma: hop = relu([pw | mut] x [W1;W2] + b2) + nf, in-place on d_out.
// A-operand staged to XOR-swizzled bf16 LDS [16][512].
// ---------------------------------------------------------------------------
__global__ __launch_bounds__(256) void k_hop_mfma(
    float* io, const float* __restrict__ mut,
    const unsigned short* __restrict__ w12, const float* __restrict__ b2,
    const float* __restrict__ nf)
{
  __shared__ alignas(16) unsigned short S2[TILE * 2 * F_];  // 16 KiB
  const int a   = blockIdx.y;
  const int r0  = blockIdx.x * TILE;
  const int tid = threadIdx.x;

  for (int row = 0; row < TILE; ++row) {
    const int r  = r0 + row;
    const int bb = r / N_, n = r - bb * N_;
    const float pv = io[((size_t)(bb * A_ + a) * N_ + n) * F_ + tid];
    const float mv = mut[((size_t)bb * N_ + n) * F_ + tid];
    const int sw = (row & 7) << 3;
    S2[(row * 512 + tid)      ^ sw] = f2bf(pv);
    S2[(row * 512 + F_ + tid) ^ sw] = f2bf(mv);
  }
  __syncthreads();

  const int lane = tid & 63, wv = tid >> 6;
  const int arow = lane & 15, kg = lane >> 4;
  const unsigned short* __restrict__ Wp = w12 + (size_t)a * KS2 * NTL * 512;
  f32x4 acc[4];
#pragma unroll
  for (int m = 0; m < 4; ++m) acc[m] = (f32x4){0.f, 0.f, 0.f, 0.f};
  const int sbase_sw = (arow & 7) << 3;
  for (int t = 0; t < KS2; ++t) {
    const int si = (arow * 512 + t * 32 + kg * 8) ^ sbase_sw;
    const bf16x8 af = *reinterpret_cast<const bf16x8*>(&S2[si]);
#pragma unroll
    for (int m = 0; m < 4; ++m) {
      const int nt = wv * 4 + m;
      const bf16x8 bf = *reinterpret_cast<const bf16x8*>(
          Wp + ((size_t)(t * NTL + nt) * 64 + lane) * 8);
      acc[m] = __builtin_amdgcn_mfma_f32_16x16x32_bf16(af, bf, acc[m], 0, 0, 0);
    }
  }

  const int orow0 = kg * 4;
#pragma unroll
  for (int m = 0; m < 4; ++m) {
    const int col = (wv * 4 + m) * 16 + arow;
    const float bb2 = b2[a * F_ + col];
#pragma unroll
    for (int rr = 0; rr < 4; ++rr) {
      const int row = orow0 + rr;
      const int r = r0 + row, bb = r / N_, n = r - bb * N_;
      const size_t o = ((size_t)(bb * A_ + a) * N_ + n) * F_ + col;
      io[o] = fmaxf(acc[m][rr] + bb2, 0.f) + nf[o];
    }
  }
}

// ---------------------------------------------------------------------------
extern "C" void kernel_launch(void* const* d_in, const int* in_sizes, int n_in,
                              void* d_out, int out_size, void* d_ws, size_t ws_size,
                              hipStream_t stream)
{
  const float* nf     = (const float*)d_in[0];
  const int*   nn_idx = (const int*)  d_in[1];
  const int*   et     = (const int*)  d_in[2];
  const float* W      = (const float*)d_in[3];
  const float* bias   = (const float*)d_in[4];
  const float* W1     = (const float*)d_in[5];
  const float* W2     = (const float*)d_in[6];
  const float* b2     = (const float*)d_in[7];
  float* out = (float*)d_out;

  unsigned short* wpk = (unsigned short*)d_ws;
  unsigned short* w12 = (unsigned short*)((char*)d_ws + OFF_W12);
  float*          mut = (float*)((char*)d_ws + OFF_MUT);

  const int packThreads = A_ * KS1 * NTL * 64 + A_ * KS2 * NTL * 64;  // 204800
  k_pack<<<dim3((packThreads + 255) / 256), 256, 0, stream>>>(W, W1, W2, wpk, w12);

  dim3 gtile(NT, A_);
  k_gather_mfma<<<gtile, 256, 0, stream>>>(nf, nn_idx, et, wpk, bias, out);
  k_mutual<<<dim3((B_ * N_ * F_) / 256), 256, 0, stream>>>(out, mut);
  k_hop_mfma<<<gtile, 256, 0, stream>>>(out, mut, w12, b2, nf);
}

// Round 3
// 57.615 us; speedup vs baseline: 3.6894x; 2.0267x over previous
//
#include <hip/hip_runtime.h>

typedef float f32x4 __attribute__((ext_vector_type(4)));
typedef __bf16 bf16x8 __attribute__((ext_vector_type(8)));
typedef unsigned short u16x4 __attribute__((ext_vector_type(4)));
typedef unsigned short u16x8 __attribute__((ext_vector_type(8)));

constexpr int B_ = 2, A_ = 5, N_ = 1000, K_ = 16, F_ = 256, E_ = 3;
constexpr int TILE = 16;
constexpr int RTOT = B_ * N_;            // 2000 rows (b,n)
constexpr int NT   = RTOT / TILE;        // 125 row-tiles
constexpr int KS1  = (E_ * F_) / 32;     // 24 k-steps, K=768
constexpr int KS2  = (2 * F_) / 32;      // 16 k-steps, K=512
constexpr int NTL  = F_ / 16;            // 16 col-tiles

// workspace layout (bytes)
constexpr size_t SZ_WPK  = (size_t)A_ * KS1 * NTL * 512 * 2;   // 1,966,080
constexpr size_t OFF_W12 = SZ_WPK;
constexpr size_t SZ_W12  = (size_t)A_ * KS2 * NTL * 512 * 2;   // 1,310,720
constexpr size_t OFF_MUT = OFF_W12 + SZ_W12;
constexpr size_t SZ_MUT  = (size_t)B_ * N_ * F_ * 4;           // 2,048,000
constexpr size_t OFF_SG  = OFF_MUT + SZ_MUT;
constexpr size_t SZ_SG   = (size_t)A_ * RTOT * (E_ * F_) * 2;  // 15,360,000
constexpr size_t OFF_CNT = OFF_SG + SZ_SG;                     // 10000 * f32x4

__device__ __forceinline__ unsigned short f2bf(float x) {
  unsigned int u = __builtin_bit_cast(unsigned int, x);
  u += 0x7fffu + ((u >> 16) & 1u);          // round-to-nearest-even
  return (unsigned short)(u >> 16);
}

// ---------------------------------------------------------------------------
// k_pack: W / [W1;W2] -> bf16 in per-lane MFMA B-fragment order (as round 2).
// ---------------------------------------------------------------------------
__global__ __launch_bounds__(256) void k_pack(
    const float* __restrict__ W, const float* __restrict__ W1,
    const float* __restrict__ W2, unsigned short* __restrict__ wpk,
    unsigned short* __restrict__ w12)
{
  const int id = blockIdx.x * 256 + threadIdx.x;
  const int T1 = A_ * KS1 * NTL * 64;   // 122880
  const int T2 = A_ * KS2 * NTL * 64;   // 81920
  if (id < T1) {
    const int lane = id & 63, nt = (id >> 6) & 15;
    const int r = id >> 10, t = r % KS1, a = r / KS1;
    const int k0 = t * 32 + (lane >> 4) * 8;
    const int n  = nt * 16 + (lane & 15);
    const float* src = W + ((size_t)a * E_ * F_ + k0) * F_ + n;
    u16x8 v;
#pragma unroll
    for (int j = 0; j < 8; ++j) v[j] = f2bf(src[(size_t)j * F_]);
    *reinterpret_cast<u16x8*>(wpk + (size_t)id * 8) = v;
  } else if (id < T1 + T2) {
    const int p = id - T1;
    const int lane = p & 63, nt = (p >> 6) & 15;
    const int r = p >> 10, t = r % KS2, a = r / KS2;
    const int k0 = t * 32 + (lane >> 4) * 8;
    const int n  = nt * 16 + (lane & 15);
    u16x8 v;
#pragma unroll
    for (int j = 0; j < 8; ++j) {
      const int k = k0 + j;
      const float s = (k < F_) ? W1[((size_t)a * F_ + k) * F_ + n]
                               : W2[((size_t)a * F_ + (k - F_)) * F_ + n];
      v[j] = f2bf(s);
    }
    *reinterpret_cast<u16x8*>(w12 + (size_t)p * 8) = v;
  }
}

// ---------------------------------------------------------------------------
// k_gather: one WARP per (a, rg) row. Gather 16 neighbors, bucket-sum by edge
// type, write bf16 row [768] to Sg with the GEMM's XOR swizzle pre-baked,
// plus counts to CNTS. 10000 tasks -> 2500 blocks: latency hidden by TLP.
// ---------------------------------------------------------------------------
__global__ __launch_bounds__(256) void k_gather(
    const float* __restrict__ nf, const int* __restrict__ nn_idx,
    const int* __restrict__ et, unsigned short* __restrict__ Sg,
    float* __restrict__ CNTS)
{
  const int task = blockIdx.x * 4 + (threadIdx.x >> 6);   // [0, 10000)
  const int lane = threadIdx.x & 63;
  const int a  = task / RTOT;
  const int rg = task - a * RTOT;
  const int bb = rg / N_;
  const int n  = rg - bb * N_;
  const int eoff = ((bb * A_ + a) * N_ + n) * K_;

  int4 iv[4], ev[4];
#pragma unroll
  for (int q = 0; q < 4; ++q) {
    iv[q] = *reinterpret_cast<const int4*>(nn_idx + eoff + q * 4);
    ev[q] = *reinterpret_cast<const int4*>(et + eoff + q * 4);
  }

  const float* __restrict__ slab =
      nf + (size_t)(bb * A_ + a) * N_ * F_ + lane * 4;
  f32x4 a0 = {0.f, 0.f, 0.f, 0.f}, a1 = a0, a2 = a0;
  int c0 = 0, c1 = 0, c2 = 0;
#pragma unroll
  for (int q = 0; q < 4; ++q) {
#pragma unroll
    for (int j = 0; j < 4; ++j) {
      const int id = ((const int*)&iv[q])[j];
      const int e  = ((const int*)&ev[q])[j];
      const f32x4 v = *reinterpret_cast<const f32x4*>(slab + (size_t)id * F_);
      if (e == 0)      { a0 += v; ++c0; }
      else if (e == 1) { a1 += v; ++c1; }
      else             { a2 += v; ++c2; }
    }
  }

  // store swizzled bf16 row: short-index (col ^ ((rg&7)<<3)) within row
  unsigned short* __restrict__ row = Sg + ((size_t)a * RTOT + rg) * 768;
  const int sw = (rg & 7) << 3;
  u16x4 p0, p1, p2;
#pragma unroll
  for (int j = 0; j < 4; ++j) {
    p0[j] = f2bf(a0[j]); p1[j] = f2bf(a1[j]); p2[j] = f2bf(a2[j]);
  }
  *reinterpret_cast<u16x4*>(row + ((0 * F_ + lane * 4) ^ sw)) = p0;
  *reinterpret_cast<u16x4*>(row + ((1 * F_ + lane * 4) ^ sw)) = p1;
  *reinterpret_cast<u16x4*>(row + ((2 * F_ + lane * 4) ^ sw)) = p2;
  if (lane == 0) {
    f32x4 c = {(float)c0, (float)c1, (float)c2, 0.f};
    *reinterpret_cast<f32x4*>(CNTS + (size_t)task * 4) = c;
  }
}

// ---------------------------------------------------------------------------
// k_gemm1: stage swizzled Sg tile (24 KB contiguous) via global_load_lds,
// then round-2 MFMA GEMM [16x768]x[768x256] -> pw (fp32 in d_out).
// ---------------------------------------------------------------------------
__global__ __launch_bounds__(256) void k_gemm1(
    const unsigned short* __restrict__ Sg, const float* __restrict__ CNTS,
    const unsigned short* __restrict__ wpk, const float* __restrict__ bias,
    float* __restrict__ pw)
{
  __shared__ alignas(16) unsigned short S[TILE * E_ * F_];  // 24 KiB
  __shared__ float CNT[TILE][4];
  const int a   = blockIdx.y;
  const int r0  = blockIdx.x * TILE;
  const int tid = threadIdx.x;

  const unsigned short* src = Sg + ((size_t)a * RTOT + r0) * 768;
#pragma unroll
  for (int it = 0; it < 6; ++it) {
    const int off = (it * 256 + tid) * 8;   // shorts; 16 B per thread
    __builtin_amdgcn_global_load_lds(
        (const __attribute__((address_space(1))) unsigned int*)(src + off),
        (__attribute__((address_space(3))) unsigned int*)(S + off), 16, 0, 0);
  }
  if (tid < TILE)
    *reinterpret_cast<f32x4*>(&CNT[tid][0]) =
        *reinterpret_cast<const f32x4*>(CNTS + (size_t)(a * RTOT + r0 + tid) * 4);
  __syncthreads();

  const int lane = tid & 63, wv = tid >> 6;
  const int arow = lane & 15, kg = lane >> 4;
  const unsigned short* __restrict__ Wp = wpk + (size_t)a * KS1 * NTL * 512;
  f32x4 acc[4];
#pragma unroll
  for (int m = 0; m < 4; ++m) acc[m] = (f32x4){0.f, 0.f, 0.f, 0.f};
  const int sbase_sw = (arow & 7) << 3;
#pragma unroll
  for (int t = 0; t < KS1; ++t) {
    const int si = (arow * 768 + t * 32 + kg * 8) ^ sbase_sw;
    const bf16x8 af = *reinterpret_cast<const bf16x8*>(&S[si]);
#pragma unroll
    for (int m = 0; m < 4; ++m) {
      const int nt = wv * 4 + m;
      const bf16x8 bf = *reinterpret_cast<const bf16x8*>(
          Wp + ((size_t)(t * NTL + nt) * 64 + lane) * 8);
      acc[m] = __builtin_amdgcn_mfma_f32_16x16x32_bf16(af, bf, acc[m], 0, 0, 0);
    }
  }

  const float* __restrict__ ba = bias + a * E_ * F_;
  const int orow0 = kg * 4;
#pragma unroll
  for (int m = 0; m < 4; ++m) {
    const int col = (wv * 4 + m) * 16 + arow;
    const float b0 = ba[col], b1 = ba[F_ + col], b2v = ba[2 * F_ + col];
#pragma unroll
    for (int rr = 0; rr < 4; ++rr) {
      const int row = orow0 + rr;
      float x = (acc[m][rr] + CNT[row][0] * b0 + CNT[row][1] * b1 +
                 CNT[row][2] * b2v) * (1.0f / K_);
      x = fmaxf(x, 0.f);
      const int r = r0 + row, bb = r / N_, n = r - bb * N_;
      pw[((size_t)(bb * A_ + a) * N_ + n) * F_ + col] = x;
    }
  }
}

// ---------------------------------------------------------------------------
// k_mutual: mut[b,n,f] = sum_a pw[b,a,n,f]
// ---------------------------------------------------------------------------
__global__ __launch_bounds__(256) void k_mutual(
    const float* __restrict__ pw, float* __restrict__ mut)
{
  const int i  = blockIdx.x * 256 + threadIdx.x;
  const int f  = i & (F_ - 1);
  const int bn = i >> 8;
  const int bb = bn / N_, n = bn - bb * N_;
  float s = 0.f;
#pragma unroll
  for (int a = 0; a < A_; ++a)
    s += pw[((size_t)(bb * A_ + a) * N_ + n) * F_ + f];
  mut[i] = s;
}

// ---------------------------------------------------------------------------
// k_hop_mfma: hop = relu([pw | mut] x [W1;W2] + b2) + nf, in-place on d_out.
// Phase 1: 4 rows per warp, f32x4 loads, fully unrolled (8 loads in flight).
// ---------------------------------------------------------------------------
__global__ __launch_bounds__(256) void k_hop_mfma(
    float* io, const float* __restrict__ mut,
    const unsigned short* __restrict__ w12, const float* __restrict__ b2,
    const float* __restrict__ nf)
{
  __shared__ alignas(16) unsigned short S2[TILE * 2 * F_];  // 16 KiB
  const int a   = blockIdx.y;
  const int r0  = blockIdx.x * TILE;
  const int tid = threadIdx.x;
  const int lane = tid & 63, wv = tid >> 6;

#pragma unroll
  for (int rr = 0; rr < 4; ++rr) {
    const int row = wv * 4 + rr;
    const int r  = r0 + row;
    const int bb = r / N_, n = r - bb * N_;
    const f32x4 pv = *reinterpret_cast<const f32x4*>(
        io + ((size_t)(bb * A_ + a) * N_ + n) * F_ + lane * 4);
    const f32x4 mv = *reinterpret_cast<const f32x4*>(
        mut + ((size_t)bb * N_ + n) * F_ + lane * 4);
    const int sw = (row & 7) << 3;
    u16x4 p4, m4;
#pragma unroll
    for (int j = 0; j < 4; ++j) { p4[j] = f2bf(pv[j]); m4[j] = f2bf(mv[j]); }
    *reinterpret_cast<u16x4*>(&S2[(row * 512 + lane * 4) ^ sw])       = p4;
    *reinterpret_cast<u16x4*>(&S2[(row * 512 + F_ + lane * 4) ^ sw])  = m4;
  }
  __syncthreads();

  const int arow = lane & 15, kg = lane >> 4;
  const unsigned short* __restrict__ Wp = w12 + (size_t)a * KS2 * NTL * 512;
  f32x4 acc[4];
#pragma unroll
  for (int m = 0; m < 4; ++m) acc[m] = (f32x4){0.f, 0.f, 0.f, 0.f};
  const int sbase_sw = (arow & 7) << 3;
#pragma unroll
  for (int t = 0; t < KS2; ++t) {
    const int si = (arow * 512 + t * 32 + kg * 8) ^ sbase_sw;
    const bf16x8 af = *reinterpret_cast<const bf16x8*>(&S2[si]);
#pragma unroll
    for (int m = 0; m < 4; ++m) {
      const int nt = wv * 4 + m;
      const bf16x8 bf = *reinterpret_cast<const bf16x8*>(
          Wp + ((size_t)(t * NTL + nt) * 64 + lane) * 8);
      acc[m] = __builtin_amdgcn_mfma_f32_16x16x32_bf16(af, bf, acc[m], 0, 0, 0);
    }
  }

  const int orow0 = kg * 4;
#pragma unroll
  for (int m = 0; m < 4; ++m) {
    const int col = (wv * 4 + m) * 16 + arow;
    const float bb2 = b2[a * F_ + col];
#pragma unroll
    for (int rr = 0; rr < 4; ++rr) {
      const int row = orow0 + rr;
      const int r = r0 + row, bb = r / N_, n = r - bb * N_;
      const size_t o = ((size_t)(bb * A_ + a) * N_ + n) * F_ + col;
      io[o] = fmaxf(acc[m][rr] + bb2, 0.f) + nf[o];
    }
  }
}

// ---------------------------------------------------------------------------
extern "C" void kernel_launch(void* const* d_in, const int* in_sizes, int n_in,
                              void* d_out, int out_size, void* d_ws, size_t ws_size,
                              hipStream_t stream)
{
  const float* nf     = (const float*)d_in[0];
  const int*   nn_idx = (const int*)  d_in[1];
  const int*   et     = (const int*)  d_in[2];
  const float* W      = (const float*)d_in[3];
  const float* bias   = (const float*)d_in[4];
  const float* W1     = (const float*)d_in[5];
  const float* W2     = (const float*)d_in[6];
  const float* b2     = (const float*)d_in[7];
  float* out = (float*)d_out;

  unsigned short* wpk  = (unsigned short*)d_ws;
  unsigned short* w12  = (unsigned short*)((char*)d_ws + OFF_W12);
  float*          mut  = (float*)((char*)d_ws + OFF_MUT);
  unsigned short* Sg   = (unsigned short*)((char*)d_ws + OFF_SG);
  float*          CNTS = (float*)((char*)d_ws + OFF_CNT);

  k_gather<<<dim3((A_ * RTOT) / 4), 256, 0, stream>>>(nf, nn_idx, et, Sg, CNTS);

  const int packThreads = A_ * KS1 * NTL * 64 + A_ * KS2 * NTL * 64;
  k_pack<<<dim3((packThreads + 255) / 256), 256, 0, stream>>>(W, W1, W2, wpk, w12);

  dim3 gtile(NT, A_);
  k_gemm1<<<gtile, 256, 0, stream>>>(Sg, CNTS, wpk, bias, out);
  k_mutual<<<dim3((B_ * N_ * F_) / 256), 256, 0, stream>>>(out, mut);
  k_hop_mfma<<<gtile, 256, 0, stream>>>(out, mut, w12, b2, nf);
}